// Round 10
// baseline (750.495 us; speedup 1.0000x reference)
//
#include <hip/hip_runtime.h>
#include <hip/hip_bf16.h>

#define B_   128
#define S_   512
#define H_   128
#define G_   512   // 4*H
#define EMB_ 128
#define NL_  9
#define CPW_ 2     // chains per workgroup

typedef __attribute__((ext_vector_type(8))) short bf16x8;
typedef __attribute__((ext_vector_type(4))) float f32x4;
typedef unsigned short ushort_t;

// padded fragment slot: chunk stride 17 (16 rows + 1 pad)
#define FRAG(c, r) ((c) * 17 + (r))

// raw barrier: LDS fence only — vmem ops (xw prefetch loads, emission
// stores) stay in flight across it.
__device__ __forceinline__ void wg_bar() {
    asm volatile("s_waitcnt lgkmcnt(0)\n\ts_barrier" ::: "memory");
}

__device__ __forceinline__ float bfbits2f(short s) {
    unsigned int u = ((unsigned int)(unsigned short)s) << 16;
    return __builtin_bit_cast(float, u);
}
__device__ __forceinline__ short f2bf(float f) {
    unsigned int u = __builtin_bit_cast(unsigned int, f);
    u += 0x7FFFu + ((u >> 16) & 1u);
    return (short)(u >> 16);
}
__device__ __forceinline__ float sigm(float x) {
    return __builtin_amdgcn_rcpf(1.f + exp2f(-1.4426950408889634f * x));
}
__device__ __forceinline__ float tanh_(float x) {
    return 1.f - 2.f * __builtin_amdgcn_rcpf(1.f + exp2f(2.8853900817779268f * x));
}

// ---------------------------------------------------------------------------
// Pre-pass GEMM: xw[dir][b*S+t][col] = emb[seq[b][t]] @ W_ih^T + b_ih + b_hh
// stored bf16. 2048 wgs x 512 thr; per wg 64 rows x 512 cols, K=128.
// ---------------------------------------------------------------------------
__global__ __launch_bounds__(512, 2)
void xw_gemm_kernel(const int* __restrict__ seq, const float* __restrict__ emb,
                    const float* __restrict__ w_ih_f, const float* __restrict__ b_ih_f,
                    const float* __restrict__ b_hh_f,
                    const float* __restrict__ w_ih_b, const float* __restrict__ b_ih_b,
                    const float* __restrict__ b_hh_b,
                    ushort_t* __restrict__ xw)
{
    __shared__ bf16x8 ldsX[64 * 17];   // 4 row-tiles x 16 chunks, padded

    const int tid  = threadIdx.x;
    const int wv   = tid >> 6;
    const int n16  = tid & 15;
    const int quad = (tid & 63) >> 4;
    const int dir  = blockIdx.x >> 10;
    const int m0   = (blockIdx.x & 1023) * 64;

    const float* wih = dir ? w_ih_b : w_ih_f;
    const float* bih = dir ? b_ih_b : b_ih_f;
    const float* bhh = dir ? b_hh_b : b_hh_f;

    // stage 64 emb rows (gathered) -> LDS in A-frag layout
    {
        int row = tid >> 3, part = tid & 7;       // 16 floats per thread
        int tok = seq[m0 + row];                  // seq flat [b][t] == row index
        const float* ep = emb + (size_t)tok * EMB_ + part * 16;
        int rt = row >> 4, rr = row & 15;
#pragma unroll
        for (int h = 0; h < 2; h++) {
            float4 a = *(const float4*)(ep + h * 8);
            float4 b = *(const float4*)(ep + h * 8 + 4);
            bf16x8 fr;
            fr[0] = f2bf(a.x); fr[1] = f2bf(a.y); fr[2] = f2bf(a.z); fr[3] = f2bf(a.w);
            fr[4] = f2bf(b.x); fr[5] = f2bf(b.y); fr[6] = f2bf(b.z); fr[7] = f2bf(b.w);
            ldsX[(rt * 16 + part * 2 + h) * 17 + rr] = fr;
        }
    }

    // B fragments + bias: wave wv owns cols [wv*64, wv*64+64)
    bf16x8 bfrag[4][4];
    float  bias[4];
#pragma unroll
    for (int nt = 0; nt < 4; nt++) {
        int col = wv * 64 + nt * 16 + n16;
        bias[nt] = bih[col] + bhh[col];
#pragma unroll
        for (int ks = 0; ks < 4; ks++) {
            const float* p = wih + col * EMB_ + ks * 32 + quad * 8;
            bf16x8 fr;
#pragma unroll
            for (int j = 0; j < 8; j++) fr[j] = f2bf(p[j]);
            bfrag[nt][ks] = fr;
        }
    }
    __syncthreads();

#pragma unroll
    for (int rt = 0; rt < 4; rt++) {
        bf16x8 af[4];
#pragma unroll
        for (int ks = 0; ks < 4; ks++)
            af[ks] = ldsX[(rt * 16 + ks * 4 + quad) * 17 + n16];
#pragma unroll
        for (int nt = 0; nt < 4; nt++) {
            f32x4 acc = {bias[nt], bias[nt], bias[nt], bias[nt]};
#pragma unroll
            for (int ks = 0; ks < 4; ks++)
                acc = __builtin_amdgcn_mfma_f32_16x16x32_bf16(af[ks], bfrag[nt][ks], acc, 0, 0, 0);
            int col = wv * 64 + nt * 16 + n16;
#pragma unroll
            for (int r = 0; r < 4; r++) {
                int grow = m0 + rt * 16 + quad * 4 + r;
                xw[((size_t)dir * (B_ * S_) + grow) * G_ + col] = (ushort_t)f2bf(acc[r]);
            }
        }
    }
}

// ---------------------------------------------------------------------------
// Recurrent LSTM, K=128 (h only; x-part pre-folded into xw as MFMA C-init).
// 128 wgs (64/dir), 2 chains, 512 thr (8 waves).
// Per step (2 lgkm-barriers):
//   P1: all waves: 4 ds_read_b128 (h frags) + 16 MFMA, gates -> LDS (b64,
//       [col][chain] packed); wave 0: +4 emission MFMAs (reuses h frags),
//       em stores fire-and-forget; quad-0 lanes prefetch xw(t+2) (VMEM).
//   P2: 256 threads: gate nonlinearity + c/h update, h -> LDS.
// ---------------------------------------------------------------------------
#define STEP_BODY(T, XWB)                                                        \
  {                                                                              \
    const int t = (T);                                                           \
    bf16x8 af[4];                                                                \
    _Pragma("unroll")                                                            \
    for (int ks = 0; ks < 4; ks++) af[ks] = ldsH[FRAG(ks * 4 + quad, n16)];      \
    f32x4 acc0 = {XWB[0], XWB[1], 0.f, 0.f};                                     \
    f32x4 acc1 = {XWB[2], XWB[3], 0.f, 0.f};                                     \
    f32x4 acc2 = {XWB[4], XWB[5], 0.f, 0.f};                                     \
    f32x4 acc3 = {XWB[6], XWB[7], 0.f, 0.f};                                     \
    /* prefetch xw(t+2) into XWB (overwrites after acc-init consumed) */         \
    if (t + 2 < S_ && quad == 0) {                                               \
      int tt2 = dir ? (S_ - 3 - t) : (t + 2);                                    \
      const ushort_t* q = xwq + (size_t)tt2 * G_;                                \
      XWB[0] = bfbits2f((short)q[c0]);        XWB[1] = bfbits2f((short)q[SGxw + c0]); \
      XWB[2] = bfbits2f((short)q[c0 + 16]);   XWB[3] = bfbits2f((short)q[SGxw + c0 + 16]); \
      XWB[4] = bfbits2f((short)q[c0 + 32]);   XWB[5] = bfbits2f((short)q[SGxw + c0 + 32]); \
      XWB[6] = bfbits2f((short)q[c0 + 48]);   XWB[7] = bfbits2f((short)q[SGxw + c0 + 48]); \
    }                                                                            \
    _Pragma("unroll")                                                            \
    for (int ks = 0; ks < 4; ks++) {                                             \
      acc0 = __builtin_amdgcn_mfma_f32_16x16x32_bf16(af[ks], bfrag[0][ks], acc0, 0, 0, 0); \
      acc1 = __builtin_amdgcn_mfma_f32_16x16x32_bf16(af[ks], bfrag[1][ks], acc1, 0, 0, 0); \
      acc2 = __builtin_amdgcn_mfma_f32_16x16x32_bf16(af[ks], bfrag[2][ks], acc2, 0, 0, 0); \
      acc3 = __builtin_amdgcn_mfma_f32_16x16x32_bf16(af[ks], bfrag[3][ks], acc3, 0, 0, 0); \
    }                                                                            \
    if (wv == 0) {  /* emission MFMA for h_{t-1}, reusing af */                  \
      f32x4 accE = {0.f, 0.f, 0.f, 0.f};                                         \
      _Pragma("unroll")                                                          \
      for (int ks = 0; ks < 4; ks++)                                             \
        accE = __builtin_amdgcn_mfma_f32_16x16x32_bf16(af[ks], bfragE[ks], accE, 0, 0, 0); \
      if (quad == 0 && n16 < NL_ && t > 0) {                                     \
        int ttp = dir ? (S_ - t) : (t - 1);                                      \
        emdir[((size_t)brow0 * S_ + ttp) * NL_ + n16] = accE[0];                 \
        emdir[((size_t)(brow0 + 1) * S_ + ttp) * NL_ + n16] = accE[1];           \
      }                                                                          \
    }                                                                            \
    if (quad == 0) {                                                             \
      float2 g0 = {acc0[0], acc0[1]}, g1 = {acc1[0], acc1[1]};                   \
      float2 g2 = {acc2[0], acc2[1]}, g3 = {acc3[0], acc3[1]};                   \
      *(float2*)(gatesL + c0 * 2)        = g0;                                   \
      *(float2*)(gatesL + (c0 + 16) * 2) = g1;                                   \
      *(float2*)(gatesL + (c0 + 32) * 2) = g2;                                   \
      *(float2*)(gatesL + (c0 + 48) * 2) = g3;                                   \
    }                                                                            \
    wg_bar();                                                                    \
    if (tid < CPW_ * H_) {                                                       \
      float ip = gatesL[uj * 2 + uc];                                            \
      float fp = gatesL[(H_ + uj) * 2 + uc];                                     \
      float gp = gatesL[(2 * H_ + uj) * 2 + uc];                                 \
      float op = gatesL[(3 * H_ + uj) * 2 + uc];                                 \
      cst = sigm(fp) * cst + sigm(ip) * tanh_(gp);                               \
      float hv = sigm(op) * tanh_(cst);                                          \
      ((short*)ldsH)[FRAG(uj >> 3, uc) * 8 + (uj & 7)] = f2bf(hv);               \
    }                                                                            \
    wg_bar();                                                                    \
  }

__global__ __launch_bounds__(512, 1)
void lstm_kernel(const ushort_t* __restrict__ xw,
                 const float* __restrict__ w_hh_f, const float* __restrict__ w_hh_b,
                 const float* __restrict__ w_out,
                 float* __restrict__ em_f, float* __restrict__ em_b)
{
    __shared__ bf16x8 ldsH[16 * 17];        // 4352 B (h, single buffer)
    __shared__ float  gatesL[G_ * CPW_];    // 4 KB, [col][chain] packed

    const int tid  = threadIdx.x;
    const int wv   = tid >> 6;
    const int n16  = tid & 15;
    const int quad = (tid & 63) >> 4;
    const int dir  = blockIdx.x >> 6;
    const int brow0 = (blockIdx.x & 63) * CPW_;

    const float* whh = dir ? w_hh_b : w_hh_f;
    float* emdir = dir ? em_b : em_f;

    // B fragments: wave wv owns gate cols [wv*64, wv*64+64), K=128 (h only)
    bf16x8 bfrag[4][4];
    const int c0 = wv * 64 + n16;
#pragma unroll
    for (int nt = 0; nt < 4; nt++) {
        int col = c0 + nt * 16;
#pragma unroll
        for (int ks = 0; ks < 4; ks++) {
            const float* p = whh + col * H_ + ks * 32 + quad * 8;
            bf16x8 fr;
#pragma unroll
            for (int j = 0; j < 8; j++) fr[j] = f2bf(p[j]);
            bfrag[nt][ks] = fr;
        }
    }
    // emission B fragments (wave 0): labels as cols, K = this dir's h half
    bf16x8 bfragE[4];
#pragma unroll
    for (int ks = 0; ks < 4; ks++) {
        bf16x8 fr = {0, 0, 0, 0, 0, 0, 0, 0};
        if (n16 < NL_) {
            const float* p = w_out + n16 * 256 + dir * 128 + ks * 32 + quad * 8;
#pragma unroll
            for (int j = 0; j < 8; j++) fr[j] = f2bf(p[j]);
        }
        bfragE[ks] = fr;
    }

    if (tid < 16 * 17) { bf16x8 z = {0,0,0,0,0,0,0,0}; ldsH[tid] = z; }

    // xw base for this wg (chain0); chain1 at +SGxw
    const ushort_t* xwq = xw + (size_t)(dir * B_ + brow0) * S_ * G_;
    const size_t SGxw = (size_t)S_ * G_;

    float xwA[8] = {0,0,0,0,0,0,0,0};
    float xwB[8] = {0,0,0,0,0,0,0,0};
    if (quad == 0) {
        int tt0 = dir ? (S_ - 1) : 0;
        int tt1 = dir ? (S_ - 2) : 1;
        const ushort_t* q0 = xwq + (size_t)tt0 * G_;
        const ushort_t* q1 = xwq + (size_t)tt1 * G_;
#pragma unroll
        for (int nt = 0; nt < 4; nt++) {
            xwA[nt * 2]     = bfbits2f((short)q0[c0 + nt * 16]);
            xwA[nt * 2 + 1] = bfbits2f((short)q0[SGxw + c0 + nt * 16]);
            xwB[nt * 2]     = bfbits2f((short)q1[c0 + nt * 16]);
            xwB[nt * 2 + 1] = bfbits2f((short)q1[SGxw + c0 + nt * 16]);
        }
    }

    float cst = 0.f;
    const int uc = tid >> 7;     // P2: chain (tid<256)
    const int uj = tid & 127;
    wg_bar();

    for (int u = 0; u < S_ / 2; u++) {
        STEP_BODY(2 * u,     xwA)
        STEP_BODY(2 * u + 1, xwB)
    }

    // final emission (h_{S-1})
    if (wv == 0) {
        bf16x8 af[4];
#pragma unroll
        for (int ks = 0; ks < 4; ks++) af[ks] = ldsH[FRAG(ks * 4 + quad, n16)];
        f32x4 accE = {0.f, 0.f, 0.f, 0.f};
#pragma unroll
        for (int ks = 0; ks < 4; ks++)
            accE = __builtin_amdgcn_mfma_f32_16x16x32_bf16(af[ks], bfragE[ks], accE, 0, 0, 0);
        if (quad == 0 && n16 < NL_) {
            int ttp = dir ? 0 : (S_ - 1);
            emdir[((size_t)brow0 * S_ + ttp) * NL_ + n16] = accE[0];
            emdir[((size_t)(brow0 + 1) * S_ + ttp) * NL_ + n16] = accE[1];
        }
    }
}

// ---------------------------------------------------------------------------
// CRF with chunked parallel scan (unchanged from R8/R9 — verified correct).
// ---------------------------------------------------------------------------
__global__ __launch_bounds__(640, 1)
void crf_kernel(const int* __restrict__ seq, const int* __restrict__ lab,
                const float* __restrict__ em_f, const float* __restrict__ em_b,
                const float* __restrict__ b_out,
                const float* __restrict__ start_t, const float* __restrict__ end_t,
                const float* __restrict__ trans, float* __restrict__ partial)
{
    __shared__ float emS[S_ * NL_];
    __shared__ float transS[NL_ * NL_];
    __shared__ float stS[NL_], enS[NL_];
    __shared__ unsigned char maskS[S_];
    __shared__ float MS[7 * 81];
    __shared__ float vS[NL_];
    __shared__ float redw[10];
    __shared__ int   redl[10];

    const int b = blockIdx.x, tid = threadIdx.x;
    const size_t base = (size_t)b * S_ * NL_;
    const float L2E = 1.4426950408889634f, LN2 = 0.6931471805599453f;

    for (int q = tid; q < S_ * NL_; q += 640)
        emS[q] = em_f[base + q] + em_b[base + q] + b_out[q % NL_];
    if (tid < NL_ * NL_) transS[tid] = trans[tid];
    if (tid < NL_) { stS[tid] = start_t[tid]; enS[tid] = end_t[tid]; }
    if (tid < S_) maskS[tid] = (seq[b * S_ + tid] != 0);
    __syncthreads();

    float np = 0.f; int myc = 0;
    if (tid < S_) {
        myc = maskS[tid];
        if (tid >= 1 && maskS[tid]) {
            int lp = lab[b * S_ + tid - 1], lc = lab[b * S_ + tid];
            np = transS[lp * NL_ + lc] + emS[tid * NL_ + lc];
        }
    }
#pragma unroll
    for (int off = 32; off; off >>= 1) {
        np  += __shfl_down(np, off, 64);
        myc += __shfl_down(myc, off, 64);
    }
    if ((tid & 63) == 0) { redw[tid >> 6] = np; redl[tid >> 6] = myc; }

    const int w = tid >> 6, l = tid & 63;
    const int lg = l / 9;
    const int g  = w * 7 + lg;
    const bool sact = (lg < 7) && (g < 64);
    const int jj = sact ? (l - lg * 9) : 0;
    const int gb = sact ? lg * 9 : 0;
    float Tc[NL_];
#pragma unroll
    for (int i = 0; i < NL_; i++) Tc[i] = transS[i * NL_ + jj];
    float sc; int tbeg, tend, cN = 0, iN = 0;
    if (sact && g == 0) {
        sc = stS[jj] + emS[jj];
        tbeg = 1; tend = 64;
    } else if (sact) {
        cN = 1 + (g - 1) / 9; iN = (g - 1) % 9;
        sc = (jj == iN) ? 0.f : -1e30f;
        tbeg = cN * 64; tend = tbeg + 64;
    } else {
        sc = -1e30f; tbeg = 448; tend = 512;
    }
    for (int t = tbeg; t < tend; t++) {
        float emv = emS[t * NL_ + jj];
        float a[NL_];
#pragma unroll
        for (int i = 0; i < NL_; i++) a[i] = __shfl(sc, gb + i, 64) + Tc[i];
        float m = a[0];
#pragma unroll
        for (int i = 1; i < NL_; i++) m = fmaxf(m, a[i]);
        float sum = 0.f;
#pragma unroll
        for (int i = 0; i < NL_; i++) sum += exp2f((a[i] - m) * L2E);
        float nxt = emv + m + LN2 * log2f(sum);
        sc = maskS[t] ? nxt : sc;
    }
    if (sact) {
        if (g == 0) vS[jj] = sc;
        else MS[(cN - 1) * 81 + iN * NL_ + jj] = sc;
    }
    __syncthreads();

    if (tid < 64) {
        const int j = (tid < NL_) ? tid : (NL_ - 1);
        float v = vS[j];
        for (int c = 1; c < 8; c++) {
            float a[NL_];
#pragma unroll
            for (int i = 0; i < NL_; i++)
                a[i] = __shfl(v, i, 64) + MS[(c - 1) * 81 + i * NL_ + j];
            float m = a[0];
#pragma unroll
            for (int i = 1; i < NL_; i++) m = fmaxf(m, a[i]);
            float sum = 0.f;
#pragma unroll
            for (int i = 0; i < NL_; i++) sum += exp2f((a[i] - m) * L2E);
            v = m + LN2 * log2f(sum);
        }
        v += enS[j];
        float mm = -1e30f, av[NL_];
#pragma unroll
        for (int i = 0; i < NL_; i++) { float vi = __shfl(v, i, 64); av[i] = vi; mm = fmaxf(mm, vi); }
        float ss = 0.f;
#pragma unroll
        for (int i = 0; i < NL_; i++) ss += exp2f((av[i] - mm) * L2E);
        if (tid == 0) {
            float num = 0.f; int len = 0;
#pragma unroll
            for (int ww = 0; ww < 10; ww++) { num += redw[ww]; len += redl[ww]; }
            int l0 = lab[b * S_];
            int ll = lab[b * S_ + len - 1];
            num += stS[l0] + emS[l0] + enS[ll];
            partial[b] = (mm + LN2 * log2f(ss)) - num;
        }
    }
}

__global__ __launch_bounds__(128)
void reduce_kernel(const float* __restrict__ partial, float* __restrict__ out)
{
    __shared__ float s[128];
    int tid = threadIdx.x;
    s[tid] = partial[tid];
    __syncthreads();
    for (int off = 64; off; off >>= 1) {
        if (tid < off) s[tid] += s[tid + off];
        __syncthreads();
    }
    if (tid == 0) out[0] = s[0];
}

extern "C" void kernel_launch(void* const* d_in, const int* in_sizes, int n_in,
                              void* d_out, int out_size, void* d_ws, size_t ws_size,
                              hipStream_t stream)
{
    const int* seq = (const int*)d_in[0];
    const int* lab = (const int*)d_in[1];
    const float* emb    = (const float*)d_in[2];
    const float* w_ih_f = (const float*)d_in[3];
    const float* w_hh_f = (const float*)d_in[4];
    const float* b_ih_f = (const float*)d_in[5];
    const float* b_hh_f = (const float*)d_in[6];
    const float* w_ih_b = (const float*)d_in[7];
    const float* w_hh_b = (const float*)d_in[8];
    const float* b_ih_b = (const float*)d_in[9];
    const float* b_hh_b = (const float*)d_in[10];
    const float* w_out  = (const float*)d_in[11];
    const float* b_out  = (const float*)d_in[12];
    const float* start_t = (const float*)d_in[13];
    const float* end_t   = (const float*)d_in[14];
    const float* trans   = (const float*)d_in[15];

    char* ws = (char*)d_ws;
    const size_t xw_bytes = (size_t)2 * B_ * S_ * G_ * sizeof(ushort_t);  // 134.2 MB
    const size_t em_bytes = (size_t)B_ * S_ * NL_ * sizeof(float);        // 2.36 MB
    ushort_t* xw   = (ushort_t*)ws;
    float* em_f    = (float*)(ws + xw_bytes);
    float* em_b    = (float*)(ws + xw_bytes + em_bytes);
    float* partial = (float*)(ws + xw_bytes + 2 * em_bytes);

    xw_gemm_kernel<<<dim3(2048), dim3(512), 0, stream>>>(seq, emb,
        w_ih_f, b_ih_f, b_hh_f, w_ih_b, b_ih_b, b_hh_b, xw);
    lstm_kernel<<<dim3(128), dim3(512), 0, stream>>>(xw, w_hh_f, w_hh_b,
        w_out, em_f, em_b);
    crf_kernel<<<dim3(B_), dim3(640), 0, stream>>>(seq, lab, em_f, em_b, b_out,
        start_t, end_t, trans, partial);
    reduce_kernel<<<dim3(1), dim3(128), 0, stream>>>(partial, (float*)d_out);
}

// Round 11
// 595.393 us; speedup vs baseline: 1.2605x; 1.2605x over previous
//
#include <hip/hip_runtime.h>
#include <hip/hip_bf16.h>

#define B_   128
#define S_   512
#define H_   128
#define G_   512   // 4*H
#define EMB_ 128
#define NL_  9
#define CPW_ 2     // chains per workgroup

typedef __attribute__((ext_vector_type(8))) short bf16x8;
typedef __attribute__((ext_vector_type(4))) float f32x4;
typedef unsigned short ushort_t;

// padded fragment slot: chunk stride 17
#define FRAG(c, r) ((c) * 17 + (r))

// LDS-only barrier: vmem ops stay in flight across it.
__device__ __forceinline__ void wg_bar() {
    asm volatile("s_waitcnt lgkmcnt(0)\n\ts_barrier" ::: "memory");
}

__device__ __forceinline__ float bfbits2f(short s) {
    unsigned int u = ((unsigned int)(unsigned short)s) << 16;
    return __builtin_bit_cast(float, u);
}
__device__ __forceinline__ short f2bf(float f) {
    unsigned int u = __builtin_bit_cast(unsigned int, f);
    u += 0x7FFFu + ((u >> 16) & 1u);
    return (short)(u >> 16);
}
__device__ __forceinline__ unsigned int pack2(float lo, float hi) {
    return (unsigned int)(unsigned short)f2bf(lo) | ((unsigned int)(unsigned short)f2bf(hi) << 16);
}
__device__ __forceinline__ float sigm(float x) {
    return __builtin_amdgcn_rcpf(1.f + exp2f(-1.4426950408889634f * x));
}
__device__ __forceinline__ float tanh_(float x) {
    return 1.f - 2.f * __builtin_amdgcn_rcpf(1.f + exp2f(2.8853900817779268f * x));
}

// ---------------------------------------------------------------------------
// xw pre-pass. Layout (ushorts):
//   xw[((((dir*64+pair)*512 + t)*8 + wv)*16 + n16)*8 + chain*4 + nt]
// i.e. the recurrent lane (wv,n16)'s 8 C-init values for step t are one
// contiguous 16B block. One wg = (dir, pair, 32 t's); both chains same t.
// Stores: one dwordx4 per row per lane — fully coalesced.
// ---------------------------------------------------------------------------
__global__ __launch_bounds__(512, 1)
void xw_gemm_kernel(const int* __restrict__ seq, const float* __restrict__ emb,
                    const float* __restrict__ w_ih_f, const float* __restrict__ b_ih_f,
                    const float* __restrict__ b_hh_f,
                    const float* __restrict__ w_ih_b, const float* __restrict__ b_ih_b,
                    const float* __restrict__ b_hh_b,
                    ushort_t* __restrict__ xw)
{
    __shared__ bf16x8 ldsX[64 * 17];

    const int tid  = threadIdx.x;
    const int wv   = tid >> 6;
    const int n16  = tid & 15;
    const int quad = (tid & 63) >> 4;
    const int dir  = blockIdx.x >> 10;
    const int rem  = blockIdx.x & 1023;
    const int pair = rem >> 4;
    const int tb   = (rem & 15) * 32;

    const float* wih = dir ? w_ih_b : w_ih_f;
    const float* bih = dir ? b_ih_b : b_ih_f;
    const float* bhh = dir ? b_hh_b : b_hh_f;

    // stage 64 rows: rows 0..31 chain0 (b=2*pair) t=tb..tb+31, rows 32..63 chain1
    {
        int row = tid >> 3, part = tid & 7;
        int b = 2 * pair + (row >> 5);
        int t = tb + (row & 31);
        int tok = seq[b * S_ + t];
        const float* ep = emb + (size_t)tok * EMB_ + part * 16;
        int rt = row >> 4, rr = row & 15;
#pragma unroll
        for (int h = 0; h < 2; h++) {
            float4 a = *(const float4*)(ep + h * 8);
            float4 b4 = *(const float4*)(ep + h * 8 + 4);
            bf16x8 fr;
            fr[0] = f2bf(a.x); fr[1] = f2bf(a.y); fr[2] = f2bf(a.z); fr[3] = f2bf(a.w);
            fr[4] = f2bf(b4.x); fr[5] = f2bf(b4.y); fr[6] = f2bf(b4.z); fr[7] = f2bf(b4.w);
            ldsX[(rt * 16 + part * 2 + h) * 17 + rr] = fr;
        }
    }

    bf16x8 bfrag[4][4];
    float  bias[4];
#pragma unroll
    for (int nt = 0; nt < 4; nt++) {
        int col = wv * 64 + nt * 16 + n16;
        bias[nt] = bih[col] + bhh[col];
#pragma unroll
        for (int ks = 0; ks < 4; ks++) {
            const float* p = wih + col * EMB_ + ks * 32 + quad * 8;
            bf16x8 fr;
#pragma unroll
            for (int j = 0; j < 8; j++) fr[j] = f2bf(p[j]);
            bfrag[nt][ks] = fr;
        }
    }
    __syncthreads();

#pragma unroll
    for (int half = 0; half < 2; half++) {
        // chain0 tile = half, chain1 tile = half+2
        f32x4 accA[4], accB[4];
        bf16x8 afA[4], afB[4];
#pragma unroll
        for (int ks = 0; ks < 4; ks++) {
            afA[ks] = ldsX[(half * 16 + ks * 4 + quad) * 17 + n16];
            afB[ks] = ldsX[((half + 2) * 16 + ks * 4 + quad) * 17 + n16];
        }
#pragma unroll
        for (int nt = 0; nt < 4; nt++) {
            f32x4 a = {bias[nt], bias[nt], bias[nt], bias[nt]};
            accA[nt] = a; accB[nt] = a;
#pragma unroll
            for (int ks = 0; ks < 4; ks++) {
                accA[nt] = __builtin_amdgcn_mfma_f32_16x16x32_bf16(afA[ks], bfrag[nt][ks], accA[nt], 0, 0, 0);
                accB[nt] = __builtin_amdgcn_mfma_f32_16x16x32_bf16(afB[ks], bfrag[nt][ks], accB[nt], 0, 0, 0);
            }
        }
#pragma unroll
        for (int r = 0; r < 4; r++) {
            int t = tb + half * 16 + quad * 4 + r;
            int4 iv;
            iv.x = (int)pack2(accA[0][r], accA[1][r]);
            iv.y = (int)pack2(accA[2][r], accA[3][r]);
            iv.z = (int)pack2(accB[0][r], accB[1][r]);
            iv.w = (int)pack2(accB[2][r], accB[3][r]);
            size_t idx = ((((size_t)dir * 64 + pair) * S_ + t) * 8 + wv) * 16 + n16;
            *(int4*)(xw + idx * 8) = iv;
        }
    }
}

// ---------------------------------------------------------------------------
// Recurrent LSTM: steady-state step has ZERO vmem instructions.
// xw staged per 16-step block into double-buffered LDS (loads at k=0,
// LDS-write at k=4). Emissions -> 32-slot LDS ring, flushed once per 16
// steps as coalesced dwordx4. A-frag reads broadcast (rows clamped to 0/1).
// ---------------------------------------------------------------------------
#define STEP(K)                                                                    \
  {                                                                                \
    const int u = m16 + (K);                                                       \
    if ((K) == 0 && m < 31) {                                                      \
      const ushort_t* gp = xwp + (size_t)(dir ? (S_ - 32 - m16) : (m16 + 16)) * 1024; \
      sA = *(const int4*)(gp + tid * 8);                                           \
      sB = *(const int4*)(gp + 4096 + tid * 8);                                    \
      sC = *(const int4*)(gp + 8192 + tid * 8);                                    \
      sD = *(const int4*)(gp + 12288 + tid * 8);                                   \
    }                                                                              \
    if ((K) == 4 && m < 31) {                                                      \
      int4* dst = (int4*)(xwL + (((m & 1) ^ 1) * 2048));                           \
      dst[tid] = sA; dst[512 + tid] = sB; dst[1024 + tid] = sC; dst[1536 + tid] = sD; \
    }                                                                              \
    if ((K) == 1 && m >= 1 && (wv == 4 || wv == 5) && lane < 36) {                 \
      int a0 = dir ? (S_ - m16) : (m16 - 16);                                      \
      int chain = wv - 4;                                                          \
      float4 fv;                                                                   \
      _Pragma("unroll")                                                            \
      for (int i = 0; i < 4; i++) {                                                \
        int q = lane * 4 + i;                                                      \
        int tq = a0 + q / 9, lq = q % 9;                                           \
        ((float*)&fv)[i] = emL[((tq & 31) * 9 + lq) * 2 + chain];                  \
      }                                                                            \
      *(float4*)(emdir + (size_t)(brow0 + chain) * (S_ * NL_) + a0 * NL_ + lane * 4) = fv; \
    }                                                                              \
    bf16x8 af0 = ldsH[FRAG(0 + quad, n16 & 1)];                                    \
    bf16x8 af1 = ldsH[FRAG(4 + quad, n16 & 1)];                                    \
    bf16x8 af2 = ldsH[FRAG(8 + quad, n16 & 1)];                                    \
    bf16x8 af3 = ldsH[FRAG(12 + quad, n16 & 1)];                                   \
    bf16x8 xv = xwL[(m & 1) * 2048 + ((dir ? (15 - (K)) : (K)) * 8 + wv) * 16 + n16]; \
    f32x4 acc0 = {bfbits2f(xv[0]), bfbits2f(xv[4]), 0.f, 0.f};                     \
    f32x4 acc1 = {bfbits2f(xv[1]), bfbits2f(xv[5]), 0.f, 0.f};                     \
    f32x4 acc2 = {bfbits2f(xv[2]), bfbits2f(xv[6]), 0.f, 0.f};                     \
    f32x4 acc3 = {bfbits2f(xv[3]), bfbits2f(xv[7]), 0.f, 0.f};                     \
    acc0 = __builtin_amdgcn_mfma_f32_16x16x32_bf16(af0, bfrag[0][0], acc0, 0, 0, 0); \
    acc1 = __builtin_amdgcn_mfma_f32_16x16x32_bf16(af0, bfrag[1][0], acc1, 0, 0, 0); \
    acc2 = __builtin_amdgcn_mfma_f32_16x16x32_bf16(af0, bfrag[2][0], acc2, 0, 0, 0); \
    acc3 = __builtin_amdgcn_mfma_f32_16x16x32_bf16(af0, bfrag[3][0], acc3, 0, 0, 0); \
    acc0 = __builtin_amdgcn_mfma_f32_16x16x32_bf16(af1, bfrag[0][1], acc0, 0, 0, 0); \
    acc1 = __builtin_amdgcn_mfma_f32_16x16x32_bf16(af1, bfrag[1][1], acc1, 0, 0, 0); \
    acc2 = __builtin_amdgcn_mfma_f32_16x16x32_bf16(af1, bfrag[2][1], acc2, 0, 0, 0); \
    acc3 = __builtin_amdgcn_mfma_f32_16x16x32_bf16(af1, bfrag[3][1], acc3, 0, 0, 0); \
    acc0 = __builtin_amdgcn_mfma_f32_16x16x32_bf16(af2, bfrag[0][2], acc0, 0, 0, 0); \
    acc1 = __builtin_amdgcn_mfma_f32_16x16x32_bf16(af2, bfrag[1][2], acc1, 0, 0, 0); \
    acc2 = __builtin_amdgcn_mfma_f32_16x16x32_bf16(af2, bfrag[2][2], acc2, 0, 0, 0); \
    acc3 = __builtin_amdgcn_mfma_f32_16x16x32_bf16(af2, bfrag[3][2], acc3, 0, 0, 0); \
    acc0 = __builtin_amdgcn_mfma_f32_16x16x32_bf16(af3, bfrag[0][3], acc0, 0, 0, 0); \
    acc1 = __builtin_amdgcn_mfma_f32_16x16x32_bf16(af3, bfrag[1][3], acc1, 0, 0, 0); \
    acc2 = __builtin_amdgcn_mfma_f32_16x16x32_bf16(af3, bfrag[2][3], acc2, 0, 0, 0); \
    acc3 = __builtin_amdgcn_mfma_f32_16x16x32_bf16(af3, bfrag[3][3], acc3, 0, 0, 0); \
    if (wv == 0) {                                                                 \
      f32x4 accE = {0.f, 0.f, 0.f, 0.f};                                           \
      accE = __builtin_amdgcn_mfma_f32_16x16x32_bf16(af0, bfragE[0], accE, 0, 0, 0); \
      accE = __builtin_amdgcn_mfma_f32_16x16x32_bf16(af1, bfragE[1], accE, 0, 0, 0); \
      accE = __builtin_amdgcn_mfma_f32_16x16x32_bf16(af2, bfragE[2], accE, 0, 0, 0); \
      accE = __builtin_amdgcn_mfma_f32_16x16x32_bf16(af3, bfragE[3], accE, 0, 0, 0); \
      if (quad == 0 && n16 < NL_ && u >= 1) {                                      \
        int tprev = dir ? (S_ - u) : (u - 1);                                      \
        float2 ev; ev.x = accE[0]; ev.y = accE[1];                                 \
        *(float2*)(emL + ((tprev & 31) * 9 + n16) * 2) = ev;                       \
      }                                                                            \
    }                                                                              \
    if (quad == 0) {                                                               \
      float2* g2 = (float2*)gatesL;                                                \
      float2 v0; v0.x = acc0[0]; v0.y = acc0[1]; g2[c0]      = v0;                 \
      float2 v1; v1.x = acc1[0]; v1.y = acc1[1]; g2[c0 + 16] = v1;                 \
      float2 v2; v2.x = acc2[0]; v2.y = acc2[1]; g2[c0 + 32] = v2;                 \
      float2 v3; v3.x = acc3[0]; v3.y = acc3[1]; g2[c0 + 48] = v3;                 \
    }                                                                              \
    wg_bar();                                                                      \
    if (tid < CPW_ * H_) {                                                         \
      float ip = gatesL[uj * 2 + uc];                                              \
      float fp = gatesL[(H_ + uj) * 2 + uc];                                       \
      float gg = gatesL[(2 * H_ + uj) * 2 + uc];                                   \
      float op = gatesL[(3 * H_ + uj) * 2 + uc];                                   \
      cst = sigm(fp) * cst + sigm(ip) * tanh_(gg);                                 \
      float hv = sigm(op) * tanh_(cst);                                            \
      ((short*)ldsH)[FRAG(uj >> 3, uc) * 8 + (uj & 7)] = f2bf(hv);                 \
    }                                                                              \
    wg_bar();                                                                      \
  }

__global__ __launch_bounds__(512, 1)
void lstm_kernel(const ushort_t* __restrict__ xw,
                 const float* __restrict__ w_hh_f, const float* __restrict__ w_hh_b,
                 const float* __restrict__ w_out,
                 float* __restrict__ em_f, float* __restrict__ em_b)
{
    __shared__ bf16x8 xwL[2 * 2048];        // 64 KB: [buf][(slot*8+wv)*16+n16]
    __shared__ bf16x8 ldsH[16 * 17];        // 4352 B
    __shared__ float  gatesL[G_ * CPW_];    // 4 KB [col](chain-packed float2)
    __shared__ float  emL[32 * NL_ * 2];    // 2304 B: [slot][label][chain]

    const int tid  = threadIdx.x;
    const int wv   = tid >> 6;
    const int lane = tid & 63;
    const int n16  = tid & 15;
    const int quad = (tid & 63) >> 4;
    const int dir  = blockIdx.x >> 6;
    const int pair = blockIdx.x & 63;
    const int brow0 = pair * CPW_;

    const float* whh = dir ? w_hh_b : w_hh_f;
    float* emdir = dir ? em_b : em_f;

    // B fragments: wave wv owns gate cols [wv*64, wv*64+64), K=128
    bf16x8 bfrag[4][4];
    const int c0 = wv * 64 + n16;
#pragma unroll
    for (int nt = 0; nt < 4; nt++) {
        int col = c0 + nt * 16;
#pragma unroll
        for (int ks = 0; ks < 4; ks++) {
            const float* p = whh + col * H_ + ks * 32 + quad * 8;
            bf16x8 fr;
#pragma unroll
            for (int j = 0; j < 8; j++) fr[j] = f2bf(p[j]);
            bfrag[nt][ks] = fr;
        }
    }
    bf16x8 bfragE[4];
#pragma unroll
    for (int ks = 0; ks < 4; ks++) {
        bf16x8 fr = {0, 0, 0, 0, 0, 0, 0, 0};
        if (n16 < NL_) {
            const float* p = w_out + n16 * 256 + dir * 128 + ks * 32 + quad * 8;
#pragma unroll
            for (int j = 0; j < 8; j++) fr[j] = f2bf(p[j]);
        }
        bfragE[ks] = fr;
    }

    if (tid < 16 * 17) { bf16x8 z = {0,0,0,0,0,0,0,0}; ldsH[tid] = z; }

    const ushort_t* xwp = xw + (size_t)(dir * 64 + pair) * ((size_t)S_ * 1024);
    // pre-stage block 0
    {
        const ushort_t* gp = xwp + (size_t)(dir ? (S_ - 16) : 0) * 1024;
        int4 a0 = *(const int4*)(gp + tid * 8);
        int4 a1 = *(const int4*)(gp + 4096 + tid * 8);
        int4 a2 = *(const int4*)(gp + 8192 + tid * 8);
        int4 a3 = *(const int4*)(gp + 12288 + tid * 8);
        int4* dst = (int4*)xwL;
        dst[tid] = a0; dst[512 + tid] = a1; dst[1024 + tid] = a2; dst[1536 + tid] = a3;
    }

    float cst = 0.f;
    const int uc = tid >> 7;
    const int uj = tid & 127;
    int4 sA, sB, sC, sD;
    wg_bar();

    for (int m = 0; m < 32; m++) {
        const int m16 = m << 4;
        STEP(0)  STEP(1)  STEP(2)  STEP(3)
        STEP(4)  STEP(5)  STEP(6)  STEP(7)
        STEP(8)  STEP(9)  STEP(10) STEP(11)
        STEP(12) STEP(13) STEP(14) STEP(15)
    }

    // final emission (h_{S-1}) -> emL, then tail flush
    if (wv == 0) {
        bf16x8 af0 = ldsH[FRAG(0 + quad, n16 & 1)];
        bf16x8 af1 = ldsH[FRAG(4 + quad, n16 & 1)];
        bf16x8 af2 = ldsH[FRAG(8 + quad, n16 & 1)];
        bf16x8 af3 = ldsH[FRAG(12 + quad, n16 & 1)];
        f32x4 accE = {0.f, 0.f, 0.f, 0.f};
        accE = __builtin_amdgcn_mfma_f32_16x16x32_bf16(af0, bfragE[0], accE, 0, 0, 0);
        accE = __builtin_amdgcn_mfma_f32_16x16x32_bf16(af1, bfragE[1], accE, 0, 0, 0);
        accE = __builtin_amdgcn_mfma_f32_16x16x32_bf16(af2, bfragE[2], accE, 0, 0, 0);
        accE = __builtin_amdgcn_mfma_f32_16x16x32_bf16(af3, bfragE[3], accE, 0, 0, 0);
        if (quad == 0 && n16 < NL_) {
            int tprev = dir ? 0 : (S_ - 1);
            float2 ev; ev.x = accE[0]; ev.y = accE[1];
            *(float2*)(emL + ((tprev & 31) * 9 + n16) * 2) = ev;
        }
    }
    wg_bar();
    if ((wv == 4 || wv == 5) && lane < 36) {
        int a0 = dir ? 0 : (S_ - 16);
        int chain = wv - 4;
        float4 fv;
#pragma unroll
        for (int i = 0; i < 4; i++) {
            int q = lane * 4 + i;
            int tq = a0 + q / 9, lq = q % 9;
            ((float*)&fv)[i] = emL[((tq & 31) * 9 + lq) * 2 + chain];
        }
        *(float4*)(emdir + (size_t)(brow0 + chain) * (S_ * NL_) + a0 * NL_ + lane * 4) = fv;
    }
}

// ---------------------------------------------------------------------------
// CRF with chunked parallel scan (unchanged — verified correct).
// ---------------------------------------------------------------------------
__global__ __launch_bounds__(640, 1)
void crf_kernel(const int* __restrict__ seq, const int* __restrict__ lab,
                const float* __restrict__ em_f, const float* __restrict__ em_b,
                const float* __restrict__ b_out,
                const float* __restrict__ start_t, const float* __restrict__ end_t,
                const float* __restrict__ trans, float* __restrict__ partial)
{
    __shared__ float emS[S_ * NL_];
    __shared__ float transS[NL_ * NL_];
    __shared__ float stS[NL_], enS[NL_];
    __shared__ unsigned char maskS[S_];
    __shared__ float MS[7 * 81];
    __shared__ float vS[NL_];
    __shared__ float redw[10];
    __shared__ int   redl[10];

    const int b = blockIdx.x, tid = threadIdx.x;
    const size_t base = (size_t)b * S_ * NL_;
    const float L2E = 1.4426950408889634f, LN2 = 0.6931471805599453f;

    for (int q = tid; q < S_ * NL_; q += 640)
        emS[q] = em_f[base + q] + em_b[base + q] + b_out[q % NL_];
    if (tid < NL_ * NL_) transS[tid] = trans[tid];
    if (tid < NL_) { stS[tid] = start_t[tid]; enS[tid] = end_t[tid]; }
    if (tid < S_) maskS[tid] = (seq[b * S_ + tid] != 0);
    __syncthreads();

    float np = 0.f; int myc = 0;
    if (tid < S_) {
        myc = maskS[tid];
        if (tid >= 1 && maskS[tid]) {
            int lp = lab[b * S_ + tid - 1], lc = lab[b * S_ + tid];
            np = transS[lp * NL_ + lc] + emS[tid * NL_ + lc];
        }
    }
#pragma unroll
    for (int off = 32; off; off >>= 1) {
        np  += __shfl_down(np, off, 64);
        myc += __shfl_down(myc, off, 64);
    }
    if ((tid & 63) == 0) { redw[tid >> 6] = np; redl[tid >> 6] = myc; }

    const int w = tid >> 6, l = tid & 63;
    const int lg = l / 9;
    const int g  = w * 7 + lg;
    const bool sact = (lg < 7) && (g < 64);
    const int jj = sact ? (l - lg * 9) : 0;
    const int gb = sact ? lg * 9 : 0;
    float Tc[NL_];
#pragma unroll
    for (int i = 0; i < NL_; i++) Tc[i] = transS[i * NL_ + jj];
    float sc; int tbeg, tend, cN = 0, iN = 0;
    if (sact && g == 0) {
        sc = stS[jj] + emS[jj];
        tbeg = 1; tend = 64;
    } else if (sact) {
        cN = 1 + (g - 1) / 9; iN = (g - 1) % 9;
        sc = (jj == iN) ? 0.f : -1e30f;
        tbeg = cN * 64; tend = tbeg + 64;
    } else {
        sc = -1e30f; tbeg = 448; tend = 512;
    }
    for (int t = tbeg; t < tend; t++) {
        float emv = emS[t * NL_ + jj];
        float a[NL_];
#pragma unroll
        for (int i = 0; i < NL_; i++) a[i] = __shfl(sc, gb + i, 64) + Tc[i];
        float m = a[0];
#pragma unroll
        for (int i = 1; i < NL_; i++) m = fmaxf(m, a[i]);
        float sum = 0.f;
#pragma unroll
        for (int i = 0; i < NL_; i++) sum += exp2f((a[i] - m) * L2E);
        float nxt = emv + m + LN2 * log2f(sum);
        sc = maskS[t] ? nxt : sc;
    }
    if (sact) {
        if (g == 0) vS[jj] = sc;
        else MS[(cN - 1) * 81 + iN * NL_ + jj] = sc;
    }
    __syncthreads();

    if (tid < 64) {
        const int j = (tid < NL_) ? tid : (NL_ - 1);
        float v = vS[j];
        for (int c = 1; c < 8; c++) {
            float a[NL_];
#pragma unroll
            for (int i = 0; i < NL_; i++)
                a[i] = __shfl(v, i, 64) + MS[(c - 1) * 81 + i * NL_ + j];
            float m = a[0];
#pragma unroll
            for (int i = 1; i < NL_; i++) m = fmaxf(m, a[i]);
            float sum = 0.f;
#pragma unroll
            for (int i = 0; i < NL_; i++) sum += exp2f((a[i] - m) * L2E);
            v = m + LN2 * log2f(sum);
        }
        v += enS[j];
        float mm = -1e30f, av[NL_];
#pragma unroll
        for (int i = 0; i < NL_; i++) { float vi = __shfl(v, i, 64); av[i] = vi; mm = fmaxf(mm, vi); }
        float ss = 0.f;
#pragma unroll
        for (int i = 0; i < NL_; i++) ss += exp2f((av[i] - mm) * L2E);
        if (tid == 0) {
            float num = 0.f; int len = 0;
#pragma unroll
            for (int ww = 0; ww < 10; ww++) { num += redw[ww]; len += redl[ww]; }
            int l0 = lab[b * S_];
            int ll = lab[b * S_ + len - 1];
            num += stS[l0] + emS[l0] + enS[ll];
            partial[b] = (mm + LN2 * log2f(ss)) - num;
        }
    }
}

__global__ __launch_bounds__(128)
void reduce_kernel(const float* __restrict__ partial, float* __restrict__ out)
{
    __shared__ float s[128];
    int tid = threadIdx.x;
    s[tid] = partial[tid];
    __syncthreads();
    for (int off = 64; off; off >>= 1) {
        if (tid < off) s[tid] += s[tid + off];
        __syncthreads();
    }
    if (tid == 0) out[0] = s[0];
}

extern "C" void kernel_launch(void* const* d_in, const int* in_sizes, int n_in,
                              void* d_out, int out_size, void* d_ws, size_t ws_size,
                              hipStream_t stream)
{
    const int* seq = (const int*)d_in[0];
    const int* lab = (const int*)d_in[1];
    const float* emb    = (const float*)d_in[2];
    const float* w_ih_f = (const float*)d_in[3];
    const float* w_hh_f = (const float*)d_in[4];
    const float* b_ih_f = (const float*)d_in[5];
    const float* b_hh_f = (const float*)d_in[6];
    const float* w_ih_b = (const float*)d_in[7];
    const float* w_hh_b = (const float*)d_in[8];
    const float* b_ih_b = (const float*)d_in[9];
    const float* b_hh_b = (const float*)d_in[10];
    const float* w_out  = (const float*)d_in[11];
    const float* b_out  = (const float*)d_in[12];
    const float* start_t = (const float*)d_in[13];
    const float* end_t   = (const float*)d_in[14];
    const float* trans   = (const float*)d_in[15];

    char* ws = (char*)d_ws;
    const size_t xw_bytes = (size_t)2 * B_ * S_ * G_ * sizeof(ushort_t);  // 134.2 MB
    const size_t em_bytes = (size_t)B_ * S_ * NL_ * sizeof(float);
    ushort_t* xw   = (ushort_t*)ws;
    float* em_f    = (float*)(ws + xw_bytes);
    float* em_b    = (float*)(ws + xw_bytes + em_bytes);
    float* partial = (float*)(ws + xw_bytes + 2 * em_bytes);

    xw_gemm_kernel<<<dim3(2048), dim3(512), 0, stream>>>(seq, emb,
        w_ih_f, b_ih_f, b_hh_f, w_ih_b, b_ih_b, b_hh_b, xw);
    lstm_kernel<<<dim3(128), dim3(512), 0, stream>>>(xw, w_hh_f, w_hh_b,
        w_out, em_f, em_b);
    crf_kernel<<<dim3(B_), dim3(640), 0, stream>>>(seq, lab, em_f, em_b, b_out,
        start_t, end_t, trans, partial);
    reduce_kernel<<<dim3(1), dim3(128), 0, stream>>>(partial, (float*)d_out);
}